// Round 11
// baseline (619.768 us; speedup 1.0000x reference)
//
#include <hip/hip_runtime.h>
#include <math.h>

#define EMBED 768
#define FFN_D 3072
#define TSEQ 4096
#define NHEAD 12
#define DHEAD 64
#define CQKV 2304   // 3*EMBED
#define NSPLIT 4
#define NQITEMS 192                    // per XCD queue: 32 qb x 6 units
#define SC2Q 0.180336880111120419f     // 0.125 * log2(e), folded into Q in QKV epilogue

typedef _Float16 f16;
typedef __attribute__((ext_vector_type(2))) _Float16 f16x2;
typedef __attribute__((ext_vector_type(4))) _Float16 f16x4;
typedef __attribute__((ext_vector_type(8))) _Float16 f16x8;
typedef __attribute__((ext_vector_type(4))) float f32x4;

#if __has_builtin(__builtin_amdgcn_exp2f)
#define EXP2(x) __builtin_amdgcn_exp2f(x)
#else
#define EXP2(x) exp2f(x)
#endif

__device__ __forceinline__ f16x2 pkrtz(float a, float b) {
    return __builtin_bit_cast(f16x2, __builtin_amdgcn_cvt_pkrtz(a, b));
}

// ---------------- fused weight prep: 64x64 transpose+convert tiles + bias concat, ONE launch
__global__ __launch_bounds__(256) void prep_kernel(const float* __restrict__ Wq,
                                                   const float* __restrict__ Wk,
                                                   const float* __restrict__ Wv,
                                                   const float* __restrict__ Wo,
                                                   const float* __restrict__ W1,
                                                   const float* __restrict__ W2,
                                                   const float* __restrict__ bq,
                                                   const float* __restrict__ bk,
                                                   const float* __restrict__ bv,
                                                   f16* __restrict__ WqkvT,
                                                   f16* __restrict__ WoT,
                                                   f16* __restrict__ W1T,
                                                   f16* __restrict__ W2T,
                                                   float* __restrict__ bqkv) {
    const int b = blockIdx.x;
    const int t = threadIdx.x;
    if (b == 1728) {   // bias concat
#pragma unroll
        for (int i = 0; i < 9; i++) {
            int idx = i * 256 + t;
            if (idx < 768) bqkv[idx] = bq[idx];
            else if (idx < 1536) bqkv[idx] = bk[idx - 768];
            else if (idx < 2304) bqkv[idx] = bv[idx - 1536];
        }
        return;
    }
    const float* W; f16* WT; int din, dout, local;
    if (b < 144)       { W = Wq; WT = WqkvT;                 din = 768;  dout = 768;  local = b; }
    else if (b < 288)  { W = Wk; WT = WqkvT + 768 * 768;     din = 768;  dout = 768;  local = b - 144; }
    else if (b < 432)  { W = Wv; WT = WqkvT + 2 * 768 * 768; din = 768;  dout = 768;  local = b - 288; }
    else if (b < 576)  { W = Wo; WT = WoT;                   din = 768;  dout = 768;  local = b - 432; }
    else if (b < 1152) { W = W1; WT = W1T;                   din = 768;  dout = 3072; local = b - 576; }
    else               { W = W2; WT = W2T;                   din = 3072; dout = 768;  local = b - 1152; }
    const int ntx = dout / 64;
    const int j0 = (local % ntx) * 64;
    const int i0 = (local / ntx) * 64;
    __shared__ float tile[64][65];
    const int tx = t & 63;
    const int ty = t >> 6;
#pragma unroll
    for (int rr = ty; rr < 64; rr += 4)
        tile[rr][tx] = W[(size_t)(i0 + rr) * dout + j0 + tx];
    __syncthreads();
    const int half = t & 31;      // owns cols 2*half, 2*half+1 of transposed row
    const int rw = t >> 5;        // 0..7
#pragma unroll
    for (int rr = rw; rr < 64; rr += 8) {
        f16x2 v = {(f16)tile[2 * half][rr], (f16)tile[2 * half + 1][rr]};
        *(f16x2*)&WT[(size_t)(j0 + rr) * din + i0 + 2 * half] = v;
    }
}

// ---------------- LayerNorm row kernel (768 wide), writes f16 only
__global__ __launch_bounds__(256) void ln_kernel(const float* __restrict__ x,
                                                 const float* __restrict__ g,
                                                 const float* __restrict__ b,
                                                 f16* __restrict__ hh) {
    const int row = blockIdx.x;
    const float* xr = x + (size_t)row * EMBED;
    const int t = threadIdx.x;
    float v0 = xr[t], v1 = xr[t + 256], v2 = xr[t + 512];
    float s = v0 + v1 + v2;
#pragma unroll
    for (int m = 1; m < 64; m <<= 1) s += __shfl_xor(s, m);
    __shared__ float red[4], red2[4];
    const int wid = t >> 6, lane = t & 63;
    if (lane == 0) red[wid] = s;
    __syncthreads();
    float mean = (red[0] + red[1] + red[2] + red[3]) * (1.0f / 768.0f);
    float d0 = v0 - mean, d1 = v1 - mean, d2 = v2 - mean;
    float ss = d0 * d0 + d1 * d1 + d2 * d2;
#pragma unroll
    for (int m = 1; m < 64; m <<= 1) ss += __shfl_xor(ss, m);
    if (lane == 0) red2[wid] = ss;
    __syncthreads();
    float inv = rsqrtf((red2[0] + red2[1] + red2[2] + red2[3]) * (1.0f / 768.0f) + 1e-5f);
    size_t base = (size_t)row * EMBED;
    hh[base + t]       = (f16)(d0 * inv * g[t] + b[t]);
    hh[base + t + 256] = (f16)(d1 * inv * g[t + 256] + b[t + 256]);
    hh[base + t + 512] = (f16)(d2 * inv * g[t + 512] + b[t + 512]);
}

// ---------------- GEMM: C[M][N] = A[M][K] * BT[N][K]^T + bias
// ATTN-STYLE STAGING (this session's proven pattern, 75us attn): global->reg
// prefetch issued a full compute-phase ahead; at the group boundary only
// barrier + ds_write (loads have landed during compute) -- no vmcnt(0) drain
// of just-issued loads (R8's exposed cost). Reg-staging frees the LDS layout
// from global_load_lds's linear-dest constraint: pad-to-72 rows (attn's Ks
// layout) -> staging ds_writes are bank-CONFLICT-FREE (144B row stride rotates
// banks 4/row) and fragment reads are 2-way (free, m136). No XOR swizzle.
// LDS: 64x128 K1 = 27.6 KB (5/CU cap), 64x64 K2 = 36.9 KB, 128x128 K1 = 36.9 KB.
// Bijective XCD-chunk swizzle (all grids %8==0). Requires K % (64*KSTEP) == 0.
// EPI 0: out fp16 (QKV: cols<768 scaled by SC2Q; cols>=1536 written TRANSPOSED to vtout)
// EPI 1: fp32 acc + bias + f16 residual     EPI 2: fp16 gelu(acc+bias)
template <int EPI, int BM, int BN, int KSTEP>
__global__ __launch_bounds__(256) void gemm_kernel(const f16* __restrict__ A,
                                                   const f16* __restrict__ BT,
                                                   const float* __restrict__ bias,
                                                   const f16* __restrict__ resh,
                                                   float* __restrict__ outf,
                                                   f16* __restrict__ outh,
                                                   f16* __restrict__ vtout,
                                                   int M, int N, int K) {
    constexpr int IM = BM / 32;
    constexpr int JN = BN / 32;
    constexpr int AC = BM / 32;   // A int4 chunks per sub-tile per thread
    constexpr int BC = BN / 32;
    __shared__ __align__(16) f16 As[KSTEP][BM][72];
    __shared__ __align__(16) f16 Bs[KSTEP][BN][72];
    const int t = threadIdx.x;
    const int nbx = gridDim.x;
    const int nwg = nbx * gridDim.y;
    int bid = blockIdx.x + blockIdx.y * nbx;
    bid = (bid & 7) * (nwg >> 3) + (bid >> 3);   // bijective XCD-chunk swizzle
    const int m0 = (bid / nbx) * BM;
    const int n0 = (bid % nbx) * BN;
    const int wid = t >> 6;
    const int lane = t & 63;
    const int wm = (wid >> 1) * (BM / 2);
    const int wn = (wid & 1) * (BN / 2);
    const int lr = lane & 15;
    const int quad = lane >> 4;
    const int sr = lane >> 3;            // 0..7 (row within an 8-row group)
    const int ccol = (lane & 7) * 8;     // 16B chunk within the 64-f16 sub-row

    f32x4 zero = {0.f, 0.f, 0.f, 0.f};
    f32x4 acc[IM][JN];
#pragma unroll
    for (int i = 0; i < IM; i++)
#pragma unroll
        for (int j = 0; j < JN; j++) acc[i][j] = zero;

    const f16* Ap = A + (size_t)(m0 + wid * (BM / 4) + sr) * K + ccol;
    const f16* Bp = BT + (size_t)(n0 + wid * (BN / 4) + sr) * K + ccol;
    const int arow = wid * (BM / 4) + sr;
    const int brow = wid * (BN / 4) + sr;

    int4 areg[KSTEP][AC], breg[KSTEP][BC];
    // prologue: prefetch group 0
#pragma unroll
    for (int sub = 0; sub < KSTEP; sub++) {
#pragma unroll
        for (int c = 0; c < AC; c++)
            areg[sub][c] = *(const int4*)(Ap + (size_t)(c * 8) * K + sub * 64);
#pragma unroll
        for (int c = 0; c < BC; c++)
            breg[sub][c] = *(const int4*)(Bp + (size_t)(c * 8) * K + sub * 64);
    }

    for (int k0 = 0; k0 < K; k0 += 64 * KSTEP) {
        __syncthreads();   // previous group's readers done
#pragma unroll
        for (int sub = 0; sub < KSTEP; sub++) {
#pragma unroll
            for (int c = 0; c < AC; c++)
                *(int4*)&As[sub][arow + c * 8][ccol] = areg[sub][c];
#pragma unroll
            for (int c = 0; c < BC; c++)
                *(int4*)&Bs[sub][brow + c * 8][ccol] = breg[sub][c];
        }
        __syncthreads();   // group visible
        if (k0 + 64 * KSTEP < K) {   // prefetch next group; flight hides under compute
            const int kn = k0 + 64 * KSTEP;
#pragma unroll
            for (int sub = 0; sub < KSTEP; sub++) {
#pragma unroll
                for (int c = 0; c < AC; c++)
                    areg[sub][c] = *(const int4*)(Ap + (size_t)(c * 8) * K + kn + sub * 64);
#pragma unroll
                for (int c = 0; c < BC; c++)
                    breg[sub][c] = *(const int4*)(Bp + (size_t)(c * 8) * K + kn + sub * 64);
            }
        }
#pragma unroll
        for (int sub = 0; sub < KSTEP; sub++) {
#pragma unroll
            for (int ks = 0; ks < 2; ks++) {
                f16x8 af[IM], bf[JN];
#pragma unroll
                for (int i = 0; i < IM; i++)
                    af[i] = *(const f16x8*)&As[sub][wm + i * 16 + lr][(ks * 4 + quad) * 8];
#pragma unroll
                for (int j = 0; j < JN; j++)
                    bf[j] = *(const f16x8*)&Bs[sub][wn + j * 16 + lr][(ks * 4 + quad) * 8];
#pragma unroll
                for (int i = 0; i < IM; i++)
#pragma unroll
                    for (int j = 0; j < JN; j++)
                        acc[i][j] = __builtin_amdgcn_mfma_f32_16x16x32_f16(bf[j], af[i], acc[i][j], 0, 0, 0);
            }
        }
    }

    // acc[i][j][r] = C[row = m0+wm+i*16+lr][col = n0+wn+j*16+quad*4+r]
    const bool vsec = (EPI == 0) && (n0 >= 2 * EMBED);   // block-uniform (BN=128 aligned)
#pragma unroll
    for (int i = 0; i < IM; i++) {
        const int row = m0 + wm + i * 16 + lr;
#pragma unroll
        for (int j = 0; j < JN; j++) {
            const int col = n0 + wn + j * 16 + quad * 4;
            const float4 bv = *(const float4*)&bias[col];
            float v0 = acc[i][j][0] + bv.x;
            float v1 = acc[i][j][1] + bv.y;
            float v2 = acc[i][j][2] + bv.z;
            float v3 = acc[i][j][3] + bv.w;
            const size_t idx = (size_t)row * N + col;
            if (EPI == 0) {
                if (vsec) {   // V section -> transposed vT[(col-1536)][row]
                    const int c0 = col - 2 * EMBED;
                    vtout[(size_t)(c0 + 0) * TSEQ + row] = (f16)v0;
                    vtout[(size_t)(c0 + 1) * TSEQ + row] = (f16)v1;
                    vtout[(size_t)(c0 + 2) * TSEQ + row] = (f16)v2;
                    vtout[(size_t)(c0 + 3) * TSEQ + row] = (f16)v3;
                } else {
                    const float qs = (col < EMBED) ? SC2Q : 1.0f;
                    f16x4 hv = {(f16)(v0 * qs), (f16)(v1 * qs), (f16)(v2 * qs), (f16)(v3 * qs)};
                    *(f16x4*)&outh[idx] = hv;
                }
            } else if (EPI == 1) {
                const f16x4 rr = *(const f16x4*)&resh[idx];
                f32x4 ov = {v0 + (float)rr[0], v1 + (float)rr[1], v2 + (float)rr[2], v3 + (float)rr[3]};
                *(f32x4*)&outf[idx] = ov;
            } else {
                f16x4 hv = {(f16)(0.5f * v0 * (1.0f + erff(v0 * 0.70710678118654752f))),
                            (f16)(0.5f * v1 * (1.0f + erff(v1 * 0.70710678118654752f))),
                            (f16)(0.5f * v2 * (1.0f + erff(v2 * 0.70710678118654752f))),
                            (f16)(0.5f * v3 * (1.0f + erff(v3 * 0.70710678118654752f)))};
                *(f16x4*)&outh[idx] = hv;
            }
        }
    }
}

// ---------------- persistent flash attention, XCD-sliced queues, NSPLIT=4
// EXACT R1 structure (75 us measured, reproduced 5x): single-buffered 64-key
// staging, kreg/vreg prefetch, two barriers/tile, f16 partials, grid 768, no
// launch_bounds clause. R2-R5 lessons: dbuf+setprio, forced occupancy (spills),
// NSPLIT=8 (2x overhead), no-LDS per-wave (latency-bound) ALL regress.
__global__ __launch_bounds__(256) void attn_kernel(const f16* __restrict__ qkv,
                                                   const f16* __restrict__ vT,
                                                   f16* __restrict__ OpartH,
                                                   float2* __restrict__ ml,
                                                   int* __restrict__ ctr) {
    __shared__ __align__(16) f16 Ks[64][72];   // [key][d]
    __shared__ __align__(16) f16 Vt[64][72];   // [d][key-permuted]
    __shared__ int s_item;
    const int t = threadIdx.x;
    const int wid = t >> 6;
    const int lane = t & 63;
    const int lr = lane & 15;
    const int quad = lane >> 4;
    const int srow = t >> 3;        // 0..31 (staging)
    const int scol = (t & 7) * 8;   // 0..56
    // permuted V destination for this thread's 8-key chunk (split into two 8B halves)
    const int pA = (t & 1) * 16 + ((t >> 1) & 1) * 4 + (t & 4) * 8;
    const int xq = blockIdx.x & 7;

    for (;;) {
        __syncthreads();
        if (t == 0) s_item = atomicAdd(&ctr[xq], 1);
        __syncthreads();
        const int item = s_item;
        if (item >= NQITEMS) return;
        const int qb = 31 - item / 6;
        const int u = xq * 6 + item % 6;     // unit 0..47
        const int h = u >> 2;
        const int sp = u & 3;
        const int q0 = qb * 128;

        const int nkb = 2 * qb + 2;
        const int chunk = (nkb + NSPLIT - 1) / NSPLIT;
        const int kb0 = sp * chunk;
        const int kb1 = min(nkb, kb0 + chunk);
        const int wrow0 = q0 + wid * 32;

        float m_i[2] = {-INFINITY, -INFINITY};
        float l_lane[2] = {0.f, 0.f};
        f32x4 zero = {0.f, 0.f, 0.f, 0.f};
        f32x4 o[4][2];
#pragma unroll
        for (int dt = 0; dt < 4; dt++)
#pragma unroll
            for (int qt = 0; qt < 2; qt++) o[dt][qt] = zero;

        f16x8 qf[2][2];
        int4 kreg[2], vreg[2];
        const f16* kbase = qkv + EMBED + (size_t)h * DHEAD;
        const f16* vbase = vT + (size_t)h * DHEAD * TSEQ;
        if (kb0 < kb1) {
#pragma unroll
            for (int qt = 0; qt < 2; qt++)
#pragma unroll
                for (int dh = 0; dh < 2; dh++)
                    qf[qt][dh] = *(const f16x8*)(qkv + (size_t)(wrow0 + qt * 16 + lr) * CQKV
                                                 + h * DHEAD + dh * 32 + quad * 8);
            const int k0 = kb0 * 64;
#pragma unroll
            for (int p = 0; p < 2; p++) {
                kreg[p] = *(const int4*)(kbase + (size_t)(k0 + p * 32 + srow) * CQKV + scol);
                vreg[p] = *(const int4*)(vbase + (size_t)(p * 32 + srow) * TSEQ + k0 + scol);
            }
        }

        for (int kb = kb0; kb < kb1; ++kb) {
            const int k0 = kb * 64;
            __syncthreads();
#pragma unroll
            for (int p = 0; p < 2; p++) {
                *(int4*)&Ks[p * 32 + srow][scol] = kreg[p];
                // permuted V write: two 8B halves (keys scol..scol+3 / scol+4..scol+7)
                *(int2*)&Vt[p * 32 + srow][pA]     = make_int2(vreg[p].x, vreg[p].y);
                *(int2*)&Vt[p * 32 + srow][pA + 8] = make_int2(vreg[p].z, vreg[p].w);
            }
            __syncthreads();
            if (kb + 1 < kb1) {
                const int kn = (kb + 1) * 64;
#pragma unroll
                for (int p = 0; p < 2; p++) {
                    kreg[p] = *(const int4*)(kbase + (size_t)(kn + p * 32 + srow) * CQKV + scol);
                    vreg[p] = *(const int4*)(vbase + (size_t)(p * 32 + srow) * TSEQ + kn + scol);
                }
            }

            if (k0 <= wrow0 + 31) {   // wave-uniform compute guard (barriers always hit)
                f32x4 s[4][2];
#pragma unroll
                for (int kt = 0; kt < 4; kt++)
#pragma unroll
                    for (int qt = 0; qt < 2; qt++) s[kt][qt] = zero;
#pragma unroll
                for (int dh = 0; dh < 2; dh++) {
#pragma unroll
                    for (int kt = 0; kt < 4; kt++) {
                        f16x8 kf = *(const f16x8*)&Ks[kt * 16 + lr][dh * 32 + quad * 8];
#pragma unroll
                        for (int qt = 0; qt < 2; qt++)
                            s[kt][qt] = __builtin_amdgcn_mfma_f32_16x16x32_f16(kf, qf[qt][dh], s[kt][qt], 0, 0, 0);
                    }
                }
                if (k0 + 63 > wrow0) {
#pragma unroll
                    for (int kt = 0; kt < 4; kt++)
#pragma unroll
                        for (int qt = 0; qt < 2; qt++)
#pragma unroll
                            for (int r = 0; r < 4; r++) {
                                int key = k0 + kt * 16 + quad * 4 + r;
                                int row = wrow0 + qt * 16 + lr;
                                if (key > row) s[kt][qt][r] = -INFINITY;
                            }
                }
                float mx[2];
#pragma unroll
                for (int qt = 0; qt < 2; qt++) {
                    float a[4];
#pragma unroll
                    for (int kt = 0; kt < 4; kt++)   // depth-2 per kt
                        a[kt] = fmaxf(fmaxf(s[kt][qt][0], s[kt][qt][1]),
                                      fmaxf(s[kt][qt][2], s[kt][qt][3]));
                    float m = fmaxf(fmaxf(a[0], a[1]), fmaxf(a[2], a[3]));
                    m = fmaxf(m, __shfl_xor(m, 16));
                    m = fmaxf(m, __shfl_xor(m, 32));
                    mx[qt] = m;
                }
                // defer-max: only rescale when some lane's tile max grew past m+4
                if (__any((mx[0] > m_i[0] + 4.f) || (mx[1] > m_i[1] + 4.f))) {
#pragma unroll
                    for (int qt = 0; qt < 2; qt++) {
                        float mn = fmaxf(m_i[qt], mx[qt]);
                        float al = EXP2(m_i[qt] - mn);
                        m_i[qt] = mn;
                        l_lane[qt] *= al;
#pragma unroll
                        for (int dt = 0; dt < 4; dt++)
#pragma unroll
                            for (int r = 0; r < 4; r++) o[dt][qt][r] *= al;
                    }
                }
                union PW { f16x8 v8; f16x2 h2[4]; };
                PW pw[2][2];
                float rs[2] = {0.f, 0.f};
#pragma unroll
                for (int kt = 0; kt < 4; kt++)
#pragma unroll
                    for (int qt = 0; qt < 2; qt++) {
                        float p0 = EXP2(s[kt][qt][0] - m_i[qt]);
                        float p1 = EXP2(s[kt][qt][1] - m_i[qt]);
                        float p2 = EXP2(s[kt][qt][2] - m_i[qt]);
                        float p3 = EXP2(s[kt][qt][3] - m_i[qt]);
                        rs[qt] += (p0 + p1) + (p2 + p3);
                        pw[kt >> 1][qt].h2[(kt & 1) * 2]     = pkrtz(p0, p1);
                        pw[kt >> 1][qt].h2[(kt & 1) * 2 + 1] = pkrtz(p2, p3);
                    }
#pragma unroll
                for (int qt = 0; qt < 2; qt++) l_lane[qt] += rs[qt];
#pragma unroll
                for (int s2 = 0; s2 < 2; s2++)
#pragma unroll
                    for (int dt = 0; dt < 4; dt++) {
                        // permuted layout -> one contiguous 16B fragment read
                        f16x8 vf = *(const f16x8*)&Vt[dt * 16 + lr][s2 * 32 + quad * 8];
#pragma unroll
                        for (int qt = 0; qt < 2; qt++)
                            o[dt][qt] = __builtin_amdgcn_mfma_f32_16x16x32_f16(vf, pw[s2][qt].v8, o[dt][qt], 0, 0, 0);
                    }
            }
        }

        float l_i[2];
#pragma unroll
        for (int qt = 0; qt < 2; qt++) {
            float v2 = l_lane[qt];
            v2 += __shfl_xor(v2, 16);
            v2 += __shfl_xor(v2, 32);
            l_i[qt] = v2;
        }
        // full-line epilogue: restage O through (now idle) Ks/Vt, emit 8x16B = 128B rows
        __syncthreads();   // all waves done reading Ks/Vt (trip count is block-uniform)
        f16* ob = ((wid & 2) ? &Vt[0][0] : &Ks[0][0]) + (wid & 1) * (32 * 72);
#pragma unroll
        for (int qt = 0; qt < 2; qt++)
#pragma unroll
            for (int dt = 0; dt < 4; dt++) {
                f16x4 oh = {(f16)o[dt][qt][0], (f16)o[dt][qt][1], (f16)o[dt][qt][2], (f16)o[dt][qt][3]};
                *(f16x4*)&ob[(qt * 16 + lr) * 72 + dt * 16 + quad * 4] = oh;
            }
        const int rl = lane >> 3;   // 0..7
        const int ck = lane & 7;    // 16B chunk within the 128B head-row
#pragma unroll
        for (int i = 0; i < 4; i++) {
            const int row_l = rl + i * 8;
            f16x8 val = *(const f16x8*)&ob[row_l * 72 + ck * 8];
            *(f16x8*)&OpartH[((size_t)sp * TSEQ + wrow0 + row_l) * EMBED + h * DHEAD + ck * 8] = val;
        }
#pragma unroll
        for (int qt = 0; qt < 2; qt++)
            if (quad == 0) {
                int row = wrow0 + qt * 16 + lr;
                ml[((size_t)sp * TSEQ + row) * NHEAD + h] = make_float2(m_i[qt], l_i[qt]);
            }
    }
}

// ---------------- merge split-K f16 partials -> ctx f16 (R8-proven version)
__global__ __launch_bounds__(128) void attn_merge_kernel(const f16* __restrict__ OpartH,
                                                         const float2* __restrict__ ml,
                                                         f16* __restrict__ ctx) {
    const int row = blockIdx.x;
    const int t = threadIdx.x;
    __shared__ float wgt[NSPLIT][NHEAD];
    if (t < NHEAD) {
        float m[NSPLIT], l[NSPLIT];
        float M = -INFINITY;
#pragma unroll
        for (int s = 0; s < NSPLIT; s++) {
            float2 v = ml[((size_t)s * TSEQ + row) * NHEAD + t];
            m[s] = v.x; l[s] = v.y;
            M = fmaxf(M, m[s]);
        }
        float L = 0.f;
        float w[NSPLIT];
#pragma unroll
        for (int s = 0; s < NSPLIT; s++) {
            w[s] = exp2f(m[s] - M);
            L += l[s] * w[s];
        }
        float rL = 1.0f / L;
#pragma unroll
        for (int s = 0; s < NSPLIT; s++) wgt[s][t] = w[s] * rL;
    }
    __syncthreads();
    if (t < 96) {   // 96 chunks of 8 f16 = 768 cols
        const int h = t >> 3;   // 8 chunks per 64-wide head
        float acc[8] = {0.f, 0.f, 0.f, 0.f, 0.f, 0.f, 0.f, 0.f};
#pragma unroll
        for (int s = 0; s < NSPLIT; s++) {
            const float w = wgt[s][h];
            f16x8 v = *(const f16x8*)&OpartH[((size_t)s * TSEQ + row) * EMBED + t * 8];
#pragma unroll
            for (int e = 0; e < 8; e++) acc[e] += w * (float)v[e];
        }
        f16x8 out;
#pragma unroll
        for (int e = 0; e < 8; e++) out[e] = (f16)acc[e];
        *(f16x8*)&ctx[(size_t)row * EMBED + t * 8] = out;
    }
}

extern "C" void kernel_launch(void* const* d_in, const int* in_sizes, int n_in,
                              void* d_out, int out_size, void* d_ws, size_t ws_size,
                              hipStream_t stream) {
    const float* x     = (const float*)d_in[0];
    const float* Wq    = (const float*)d_in[1];
    const float* bq    = (const float*)d_in[2];
    const float* Wk    = (const float*)d_in[3];
    const float* bk    = (const float*)d_in[4];
    const float* Wv    = (const float*)d_in[5];
    const float* bv    = (const float*)d_in[6];
    const float* Wo    = (const float*)d_in[7];
    const float* bo    = (const float*)d_in[8];
    const float* ln1_g = (const float*)d_in[9];
    const float* ln1_b = (const float*)d_in[10];
    const float* ln2_g = (const float*)d_in[11];
    const float* ln2_b = (const float*)d_in[12];
    const float* W1    = (const float*)d_in[13];
    const float* b1    = (const float*)d_in[14];
    const float* W2    = (const float*)d_in[15];
    const float* b2    = (const float*)d_in[16];

    char* p = (char*)d_ws;
    auto alloc = [&](size_t bytes) -> void* {
        void* r = (void*)p;
        p += (bytes + 255) & ~(size_t)255;
        return r;
    };
    f16*   WqkvT = (f16*)alloc((size_t)CQKV * EMBED * 2);
    f16*   WoT   = (f16*)alloc((size_t)EMBED * EMBED * 2);
    f16*   W1T   = (f16*)alloc((size_t)FFN_D * EMBED * 2);
    f16*   W2T   = (f16*)alloc((size_t)EMBED * FFN_D * 2);
    float* bqkv  = (float*)alloc((size_t)CQKV * 4);
    f16*   hh    = (f16*)alloc((size_t)TSEQ * EMBED * 2);
    f16*   qkv   = (f16*)alloc((size_t)TSEQ * CQKV * 2);   // V third unused (vT direct)
    f16*   vT    = (f16*)alloc((size_t)EMBED * TSEQ * 2);
    f16*   ctx   = (f16*)alloc((size_t)TSEQ * EMBED * 2);
    float* x2    = (float*)alloc((size_t)TSEQ * EMBED * 4);
    f16*   h2h   = (f16*)alloc((size_t)TSEQ * EMBED * 2);
    f16*   m1    = (f16*)alloc((size_t)TSEQ * FFN_D * 2);
    int*   ctr   = (int*)alloc(256);

    // aliases (lifetime-disjoint):
    //   OpartH (25.2 MB f16) = m1 region  (attn+merge finish before FFN1 writes m1)
    //   mlbuf  (1.5 MB)      = x2 region  (merge reads before Wo writes x2)
    f16*    OpartH = m1;
    float2* mlbuf  = (float2*)x2;

    dim3 blk(256);
    prep_kernel<<<dim3(1729), blk, 0, stream>>>(Wq, Wk, Wv, Wo, W1, W2, bq, bk, bv,
                                                WqkvT, WoT, W1T, W2T, bqkv);
    // LN1 -> hh (f16)
    ln_kernel<<<dim3(TSEQ), blk, 0, stream>>>(x, ln1_g, ln1_b, hh);
    // QKV fused GEMM 64x128 K1 reg-prefetch (27.6 KB LDS, 5/CU cap): grid 18x64 = 1152
    gemm_kernel<0, 64, 128, 1><<<dim3(CQKV / 128, TSEQ / 64), blk, 0, stream>>>(
        hh, WqkvT, bqkv, nullptr, nullptr, qkv, vT, TSEQ, CQKV, EMBED);
    // persistent attention (R1 structure: 8 XCD queues, NSPLIT=4, grid 768) + merge
    (void)hipMemsetAsync(ctr, 0, 256, stream);
    attn_kernel<<<dim3(768), blk, 0, stream>>>(qkv, vT, OpartH, mlbuf, ctr);
    attn_merge_kernel<<<dim3(TSEQ), dim3(128), 0, stream>>>(OpartH, mlbuf, ctx);
    // Wo GEMM 64x64 K2 reg-prefetch (36.9 KB, 4/CU cap) + f16 residual(hh) -> fp32 x2:
    // grid 768 = 3/CU exact
    gemm_kernel<1, 64, 64, 2><<<dim3(EMBED / 64, TSEQ / 64), blk, 0, stream>>>(
        ctx, WoT, bo, hh, x2, nullptr, nullptr, TSEQ, EMBED, EMBED);
    // LN2 -> h2h (f16)
    ln_kernel<<<dim3(TSEQ), blk, 0, stream>>>(x2, ln2_g, ln2_b, h2h);
    // FFN1 + gelu -> m1: 128x128 K1 reg-prefetch (36.9 KB), grid 24x32 = 768 = 3/CU
    gemm_kernel<2, 128, 128, 1><<<dim3(FFN_D / 128, TSEQ / 128), blk, 0, stream>>>(
        h2h, W1T, b1, nullptr, nullptr, m1, nullptr, TSEQ, FFN_D, EMBED);
    // FFN2 GEMM 64x64 K2 reg-prefetch + f16 residual(h2h) -> fp32 d_out: grid 768
    gemm_kernel<1, 64, 64, 2><<<dim3(EMBED / 64, TSEQ / 64), blk, 0, stream>>>(
        m1, W2T, b2, h2h, (float*)d_out, nullptr, nullptr, TSEQ, EMBED, FFN_D);
}

// Round 12
// 298.573 us; speedup vs baseline: 2.0758x; 2.0758x over previous
//
#include <hip/hip_runtime.h>
#include <math.h>

#define EMBED 768
#define FFN_D 3072
#define TSEQ 4096
#define NHEAD 12
#define DHEAD 64
#define CQKV 2304   // 3*EMBED
#define NSPLIT 4
#define NQITEMS 192                    // per XCD queue: 32 qb x 6 units
#define SC2Q 0.180336880111120419f     // 0.125 * log2(e), folded into Q in QKV epilogue

typedef _Float16 f16;
typedef __attribute__((ext_vector_type(2))) _Float16 f16x2;
typedef __attribute__((ext_vector_type(4))) _Float16 f16x4;
typedef __attribute__((ext_vector_type(8))) _Float16 f16x8;
typedef __attribute__((ext_vector_type(4))) float f32x4;

#if __has_builtin(__builtin_amdgcn_exp2f)
#define EXP2(x) __builtin_amdgcn_exp2f(x)
#else
#define EXP2(x) exp2f(x)
#endif

__device__ __forceinline__ f16x2 pkrtz(float a, float b) {
    return __builtin_bit_cast(f16x2, __builtin_amdgcn_cvt_pkrtz(a, b));
}

// async global->LDS, 16B per lane; lds base wave-uniform, lane i lands at base + i*16
__device__ __forceinline__ void gload16(const f16* g, f16* lds) {
    __builtin_amdgcn_global_load_lds((const __attribute__((address_space(1))) void*)g,
                                     (__attribute__((address_space(3))) void*)lds, 16, 0, 0);
}

// ---------------- fused weight prep: 64x64 transpose+convert tiles + bias concat, ONE launch
__global__ __launch_bounds__(256) void prep_kernel(const float* __restrict__ Wq,
                                                   const float* __restrict__ Wk,
                                                   const float* __restrict__ Wv,
                                                   const float* __restrict__ Wo,
                                                   const float* __restrict__ W1,
                                                   const float* __restrict__ W2,
                                                   const float* __restrict__ bq,
                                                   const float* __restrict__ bk,
                                                   const float* __restrict__ bv,
                                                   f16* __restrict__ WqkvT,
                                                   f16* __restrict__ WoT,
                                                   f16* __restrict__ W1T,
                                                   f16* __restrict__ W2T,
                                                   float* __restrict__ bqkv) {
    const int b = blockIdx.x;
    const int t = threadIdx.x;
    if (b == 1728) {   // bias concat
#pragma unroll
        for (int i = 0; i < 9; i++) {
            int idx = i * 256 + t;
            if (idx < 768) bqkv[idx] = bq[idx];
            else if (idx < 1536) bqkv[idx] = bk[idx - 768];
            else if (idx < 2304) bqkv[idx] = bv[idx - 1536];
        }
        return;
    }
    const float* W; f16* WT; int din, dout, local;
    if (b < 144)       { W = Wq; WT = WqkvT;                 din = 768;  dout = 768;  local = b; }
    else if (b < 288)  { W = Wk; WT = WqkvT + 768 * 768;     din = 768;  dout = 768;  local = b - 144; }
    else if (b < 432)  { W = Wv; WT = WqkvT + 2 * 768 * 768; din = 768;  dout = 768;  local = b - 288; }
    else if (b < 576)  { W = Wo; WT = WoT;                   din = 768;  dout = 768;  local = b - 432; }
    else if (b < 1152) { W = W1; WT = W1T;                   din = 768;  dout = 3072; local = b - 576; }
    else               { W = W2; WT = W2T;                   din = 3072; dout = 768;  local = b - 1152; }
    const int ntx = dout / 64;
    const int j0 = (local % ntx) * 64;
    const int i0 = (local / ntx) * 64;
    __shared__ float tile[64][65];
    const int tx = t & 63;
    const int ty = t >> 6;
#pragma unroll
    for (int rr = ty; rr < 64; rr += 4)
        tile[rr][tx] = W[(size_t)(i0 + rr) * dout + j0 + tx];
    __syncthreads();
    const int half = t & 31;      // owns cols 2*half, 2*half+1 of transposed row
    const int rw = t >> 5;        // 0..7
#pragma unroll
    for (int rr = rw; rr < 64; rr += 8) {
        f16x2 v = {(f16)tile[2 * half][rr], (f16)tile[2 * half + 1][rr]};
        *(f16x2*)&WT[(size_t)(j0 + rr) * din + i0 + 2 * half] = v;
    }
}

// ---------------- LayerNorm row kernel (768 wide), writes f16 only
__global__ __launch_bounds__(256) void ln_kernel(const float* __restrict__ x,
                                                 const float* __restrict__ g,
                                                 const float* __restrict__ b,
                                                 f16* __restrict__ hh) {
    const int row = blockIdx.x;
    const float* xr = x + (size_t)row * EMBED;
    const int t = threadIdx.x;
    float v0 = xr[t], v1 = xr[t + 256], v2 = xr[t + 512];
    float s = v0 + v1 + v2;
#pragma unroll
    for (int m = 1; m < 64; m <<= 1) s += __shfl_xor(s, m);
    __shared__ float red[4], red2[4];
    const int wid = t >> 6, lane = t & 63;
    if (lane == 0) red[wid] = s;
    __syncthreads();
    float mean = (red[0] + red[1] + red[2] + red[3]) * (1.0f / 768.0f);
    float d0 = v0 - mean, d1 = v1 - mean, d2 = v2 - mean;
    float ss = d0 * d0 + d1 * d1 + d2 * d2;
#pragma unroll
    for (int m = 1; m < 64; m <<= 1) ss += __shfl_xor(ss, m);
    if (lane == 0) red2[wid] = ss;
    __syncthreads();
    float inv = rsqrtf((red2[0] + red2[1] + red2[2] + red2[3]) * (1.0f / 768.0f) + 1e-5f);
    size_t base = (size_t)row * EMBED;
    hh[base + t]       = (f16)(d0 * inv * g[t] + b[t]);
    hh[base + t + 256] = (f16)(d1 * inv * g[t + 256] + b[t + 256]);
    hh[base + t + 512] = (f16)(d2 * inv * g[t + 512] + b[t + 512]);
}

// ---------------- GEMM: C[M][N] = A[M][K] * BT[N][K]^T + bias
// R8-VERIFIED OPTIMUM (308.9 us total). Two-barrier KSTEP loop: stage KSTEP
// 64-wide sub-tiles via global_load_lds per barrier pair, compute back-to-back.
// Session ledger: KSTEP1(318.6) < KSTEP2(308.9) > KSTEP3(318.7); single-barrier
// dbuf (327.7) worse; reg-prefetch (619.8, VGPR-spill) catastrophic. gload_lds
// is the only staging discipline the compiler handles well here (m151).
// LDS: 64x64 K2 -> 32.8 KB, 64x128 K2 -> 49.2 KB, 128x128 K1 -> 32.8 KB.
// XOR-swizzled LDS, swapped MFMA operands, bijective XCD-chunk swizzle.
// EPI 0: out fp16 (QKV: cols<768 scaled by SC2Q; cols>=1536 written TRANSPOSED to vtout)
// EPI 1: fp32 acc + bias + f16 residual     EPI 2: fp16 gelu(acc+bias)
template <int EPI, int BM, int BN, int KSTEP>
__global__ __launch_bounds__(256) void gemm_kernel(const f16* __restrict__ A,
                                                   const f16* __restrict__ BT,
                                                   const float* __restrict__ bias,
                                                   const f16* __restrict__ resh,
                                                   float* __restrict__ outf,
                                                   f16* __restrict__ outh,
                                                   f16* __restrict__ vtout,
                                                   int M, int N, int K) {
    constexpr int IM = BM / 32;
    constexpr int JN = BN / 32;
    __shared__ __align__(16) f16 As[KSTEP][BM][64];
    __shared__ __align__(16) f16 Bs[KSTEP][BN][64];
    const int t = threadIdx.x;
    const int nbx = gridDim.x;
    const int nwg = nbx * gridDim.y;
    int bid = blockIdx.x + blockIdx.y * nbx;
    bid = (bid & 7) * (nwg >> 3) + (bid >> 3);   // bijective XCD-chunk swizzle
    const int m0 = (bid / nbx) * BM;
    const int n0 = (bid % nbx) * BN;
    const int wid = t >> 6;
    const int lane = t & 63;
    const int wm = (wid >> 1) * (BM / 2);
    const int wn = (wid & 1) * (BN / 2);
    const int lr = lane & 15;
    const int quad = lane >> 4;
    const int sr = lane >> 3;            // 0..7 (row within an 8-row DMA call)
    const int scn = (lane & 7) ^ sr;     // swizzled source chunk (8 f16 per chunk)
    const int xv = lr & 7;               // read-side xor

    f32x4 zero = {0.f, 0.f, 0.f, 0.f};
    f32x4 acc[IM][JN];
#pragma unroll
    for (int i = 0; i < IM; i++)
#pragma unroll
        for (int j = 0; j < JN; j++) acc[i][j] = zero;

    const f16* Ap = A + (size_t)(m0 + wid * (BM / 4) + sr) * K + scn * 8;
    const f16* Bp = BT + (size_t)(n0 + wid * (BN / 4) + sr) * K + scn * 8;

    for (int k0 = 0; k0 < K; k0 += 64 * KSTEP) {
        __syncthreads();
#pragma unroll
        for (int sub = 0; sub < KSTEP; sub++) {
#pragma unroll
            for (int c = 0; c < BM / 32; c++)
                gload16(Ap + (size_t)(c * 8) * K + k0 + sub * 64, &As[sub][wid * (BM / 4) + c * 8][0]);
#pragma unroll
            for (int c = 0; c < BN / 32; c++)
                gload16(Bp + (size_t)(c * 8) * K + k0 + sub * 64, &Bs[sub][wid * (BN / 4) + c * 8][0]);
        }
        __syncthreads();
#pragma unroll
        for (int sub = 0; sub < KSTEP; sub++) {
#pragma unroll
            for (int ks = 0; ks < 2; ks++) {
                f16x8 af[IM], bf[JN];
#pragma unroll
                for (int i = 0; i < IM; i++)
                    af[i] = *(const f16x8*)&As[sub][wm + i * 16 + lr][((ks * 4 + quad) ^ xv) * 8];
#pragma unroll
                for (int j = 0; j < JN; j++)
                    bf[j] = *(const f16x8*)&Bs[sub][wn + j * 16 + lr][((ks * 4 + quad) ^ xv) * 8];
#pragma unroll
                for (int i = 0; i < IM; i++)
#pragma unroll
                    for (int j = 0; j < JN; j++)
                        acc[i][j] = __builtin_amdgcn_mfma_f32_16x16x32_f16(bf[j], af[i], acc[i][j], 0, 0, 0);
            }
        }
    }

    // acc[i][j][r] = C[row = m0+wm+i*16+lr][col = n0+wn+j*16+quad*4+r]
    const bool vsec = (EPI == 0) && (n0 >= 2 * EMBED);   // block-uniform (BN=128 aligned)
#pragma unroll
    for (int i = 0; i < IM; i++) {
        const int row = m0 + wm + i * 16 + lr;
#pragma unroll
        for (int j = 0; j < JN; j++) {
            const int col = n0 + wn + j * 16 + quad * 4;
            const float4 bv = *(const float4*)&bias[col];
            float v0 = acc[i][j][0] + bv.x;
            float v1 = acc[i][j][1] + bv.y;
            float v2 = acc[i][j][2] + bv.z;
            float v3 = acc[i][j][3] + bv.w;
            const size_t idx = (size_t)row * N + col;
            if (EPI == 0) {
                if (vsec) {   // V section -> transposed vT[(col-1536)][row]
                    const int c0 = col - 2 * EMBED;
                    vtout[(size_t)(c0 + 0) * TSEQ + row] = (f16)v0;
                    vtout[(size_t)(c0 + 1) * TSEQ + row] = (f16)v1;
                    vtout[(size_t)(c0 + 2) * TSEQ + row] = (f16)v2;
                    vtout[(size_t)(c0 + 3) * TSEQ + row] = (f16)v3;
                } else {
                    const float qs = (col < EMBED) ? SC2Q : 1.0f;
                    f16x4 hv = {(f16)(v0 * qs), (f16)(v1 * qs), (f16)(v2 * qs), (f16)(v3 * qs)};
                    *(f16x4*)&outh[idx] = hv;
                }
            } else if (EPI == 1) {
                const f16x4 rr = *(const f16x4*)&resh[idx];
                f32x4 ov = {v0 + (float)rr[0], v1 + (float)rr[1], v2 + (float)rr[2], v3 + (float)rr[3]};
                *(f32x4*)&outf[idx] = ov;
            } else {
                f16x4 hv = {(f16)(0.5f * v0 * (1.0f + erff(v0 * 0.70710678118654752f))),
                            (f16)(0.5f * v1 * (1.0f + erff(v1 * 0.70710678118654752f))),
                            (f16)(0.5f * v2 * (1.0f + erff(v2 * 0.70710678118654752f))),
                            (f16)(0.5f * v3 * (1.0f + erff(v3 * 0.70710678118654752f)))};
                *(f16x4*)&outh[idx] = hv;
            }
        }
    }
}

// ---------------- persistent flash attention, XCD-sliced queues, NSPLIT=4
// EXACT R1 structure (75 us measured, reproduced 6x): single-buffered 64-key
// staging, kreg/vreg prefetch, two barriers/tile, f16 partials, grid 768, no
// launch_bounds clause. R2-R5 lessons: dbuf+setprio, forced occupancy (spills),
// NSPLIT=8 (2x overhead), no-LDS per-wave (latency-bound) ALL regress.
__global__ __launch_bounds__(256) void attn_kernel(const f16* __restrict__ qkv,
                                                   const f16* __restrict__ vT,
                                                   f16* __restrict__ OpartH,
                                                   float2* __restrict__ ml,
                                                   int* __restrict__ ctr) {
    __shared__ __align__(16) f16 Ks[64][72];   // [key][d]
    __shared__ __align__(16) f16 Vt[64][72];   // [d][key-permuted]
    __shared__ int s_item;
    const int t = threadIdx.x;
    const int wid = t >> 6;
    const int lane = t & 63;
    const int lr = lane & 15;
    const int quad = lane >> 4;
    const int srow = t >> 3;        // 0..31 (staging)
    const int scol = (t & 7) * 8;   // 0..56
    // permuted V destination for this thread's 8-key chunk (split into two 8B halves)
    const int pA = (t & 1) * 16 + ((t >> 1) & 1) * 4 + (t & 4) * 8;
    const int xq = blockIdx.x & 7;

    for (;;) {
        __syncthreads();
        if (t == 0) s_item = atomicAdd(&ctr[xq], 1);
        __syncthreads();
        const int item = s_item;
        if (item >= NQITEMS) return;
        const int qb = 31 - item / 6;
        const int u = xq * 6 + item % 6;     // unit 0..47
        const int h = u >> 2;
        const int sp = u & 3;
        const int q0 = qb * 128;

        const int nkb = 2 * qb + 2;
        const int chunk = (nkb + NSPLIT - 1) / NSPLIT;
        const int kb0 = sp * chunk;
        const int kb1 = min(nkb, kb0 + chunk);
        const int wrow0 = q0 + wid * 32;

        float m_i[2] = {-INFINITY, -INFINITY};
        float l_lane[2] = {0.f, 0.f};
        f32x4 zero = {0.f, 0.f, 0.f, 0.f};
        f32x4 o[4][2];
#pragma unroll
        for (int dt = 0; dt < 4; dt++)
#pragma unroll
            for (int qt = 0; qt < 2; qt++) o[dt][qt] = zero;

        f16x8 qf[2][2];
        int4 kreg[2], vreg[2];
        const f16* kbase = qkv + EMBED + (size_t)h * DHEAD;
        const f16* vbase = vT + (size_t)h * DHEAD * TSEQ;
        if (kb0 < kb1) {
#pragma unroll
            for (int qt = 0; qt < 2; qt++)
#pragma unroll
                for (int dh = 0; dh < 2; dh++)
                    qf[qt][dh] = *(const f16x8*)(qkv + (size_t)(wrow0 + qt * 16 + lr) * CQKV
                                                 + h * DHEAD + dh * 32 + quad * 8);
            const int k0 = kb0 * 64;
#pragma unroll
            for (int p = 0; p < 2; p++) {
                kreg[p] = *(const int4*)(kbase + (size_t)(k0 + p * 32 + srow) * CQKV + scol);
                vreg[p] = *(const int4*)(vbase + (size_t)(p * 32 + srow) * TSEQ + k0 + scol);
            }
        }

        for (int kb = kb0; kb < kb1; ++kb) {
            const int k0 = kb * 64;
            __syncthreads();
#pragma unroll
            for (int p = 0; p < 2; p++) {
                *(int4*)&Ks[p * 32 + srow][scol] = kreg[p];
                // permuted V write: two 8B halves (keys scol..scol+3 / scol+4..scol+7)
                *(int2*)&Vt[p * 32 + srow][pA]     = make_int2(vreg[p].x, vreg[p].y);
                *(int2*)&Vt[p * 32 + srow][pA + 8] = make_int2(vreg[p].z, vreg[p].w);
            }
            __syncthreads();
            if (kb + 1 < kb1) {
                const int kn = (kb + 1) * 64;
#pragma unroll
                for (int p = 0; p < 2; p++) {
                    kreg[p] = *(const int4*)(kbase + (size_t)(kn + p * 32 + srow) * CQKV + scol);
                    vreg[p] = *(const int4*)(vbase + (size_t)(p * 32 + srow) * TSEQ + kn + scol);
                }
            }

            if (k0 <= wrow0 + 31) {   // wave-uniform compute guard (barriers always hit)
                f32x4 s[4][2];
#pragma unroll
                for (int kt = 0; kt < 4; kt++)
#pragma unroll
                    for (int qt = 0; qt < 2; qt++) s[kt][qt] = zero;
#pragma unroll
                for (int dh = 0; dh < 2; dh++) {
#pragma unroll
                    for (int kt = 0; kt < 4; kt++) {
                        f16x8 kf = *(const f16x8*)&Ks[kt * 16 + lr][dh * 32 + quad * 8];
#pragma unroll
                        for (int qt = 0; qt < 2; qt++)
                            s[kt][qt] = __builtin_amdgcn_mfma_f32_16x16x32_f16(kf, qf[qt][dh], s[kt][qt], 0, 0, 0);
                    }
                }
                if (k0 + 63 > wrow0) {
#pragma unroll
                    for (int kt = 0; kt < 4; kt++)
#pragma unroll
                        for (int qt = 0; qt < 2; qt++)
#pragma unroll
                            for (int r = 0; r < 4; r++) {
                                int key = k0 + kt * 16 + quad * 4 + r;
                                int row = wrow0 + qt * 16 + lr;
                                if (key > row) s[kt][qt][r] = -INFINITY;
                            }
                }
                float mx[2];
#pragma unroll
                for (int qt = 0; qt < 2; qt++) {
                    float a[4];
#pragma unroll
                    for (int kt = 0; kt < 4; kt++)   // depth-2 per kt
                        a[kt] = fmaxf(fmaxf(s[kt][qt][0], s[kt][qt][1]),
                                      fmaxf(s[kt][qt][2], s[kt][qt][3]));
                    float m = fmaxf(fmaxf(a[0], a[1]), fmaxf(a[2], a[3]));
                    m = fmaxf(m, __shfl_xor(m, 16));
                    m = fmaxf(m, __shfl_xor(m, 32));
                    mx[qt] = m;
                }
                // defer-max: only rescale when some lane's tile max grew past m+4
                if (__any((mx[0] > m_i[0] + 4.f) || (mx[1] > m_i[1] + 4.f))) {
#pragma unroll
                    for (int qt = 0; qt < 2; qt++) {
                        float mn = fmaxf(m_i[qt], mx[qt]);
                        float al = EXP2(m_i[qt] - mn);
                        m_i[qt] = mn;
                        l_lane[qt] *= al;
#pragma unroll
                        for (int dt = 0; dt < 4; dt++)
#pragma unroll
                            for (int r = 0; r < 4; r++) o[dt][qt][r] *= al;
                    }
                }
                union PW { f16x8 v8; f16x2 h2[4]; };
                PW pw[2][2];
                float rs[2] = {0.f, 0.f};
#pragma unroll
                for (int kt = 0; kt < 4; kt++)
#pragma unroll
                    for (int qt = 0; qt < 2; qt++) {
                        float p0 = EXP2(s[kt][qt][0] - m_i[qt]);
                        float p1 = EXP2(s[kt][qt][1] - m_i[qt]);
                        float p2 = EXP2(s[kt][qt][2] - m_i[qt]);
                        float p3 = EXP2(s[kt][qt][3] - m_i[qt]);
                        rs[qt] += (p0 + p1) + (p2 + p3);
                        pw[kt >> 1][qt].h2[(kt & 1) * 2]     = pkrtz(p0, p1);
                        pw[kt >> 1][qt].h2[(kt & 1) * 2 + 1] = pkrtz(p2, p3);
                    }
#pragma unroll
                for (int qt = 0; qt < 2; qt++) l_lane[qt] += rs[qt];
#pragma unroll
                for (int s2 = 0; s2 < 2; s2++)
#pragma unroll
                    for (int dt = 0; dt < 4; dt++) {
                        // permuted layout -> one contiguous 16B fragment read
                        f16x8 vf = *(const f16x8*)&Vt[dt * 16 + lr][s2 * 32 + quad * 8];
#pragma unroll
                        for (int qt = 0; qt < 2; qt++)
                            o[dt][qt] = __builtin_amdgcn_mfma_f32_16x16x32_f16(vf, pw[s2][qt].v8, o[dt][qt], 0, 0, 0);
                    }
            }
        }

        float l_i[2];
#pragma unroll
        for (int qt = 0; qt < 2; qt++) {
            float v2 = l_lane[qt];
            v2 += __shfl_xor(v2, 16);
            v2 += __shfl_xor(v2, 32);
            l_i[qt] = v2;
        }
        // full-line epilogue: restage O through (now idle) Ks/Vt, emit 8x16B = 128B rows
        __syncthreads();   // all waves done reading Ks/Vt (trip count is block-uniform)
        f16* ob = ((wid & 2) ? &Vt[0][0] : &Ks[0][0]) + (wid & 1) * (32 * 72);
#pragma unroll
        for (int qt = 0; qt < 2; qt++)
#pragma unroll
            for (int dt = 0; dt < 4; dt++) {
                f16x4 oh = {(f16)o[dt][qt][0], (f16)o[dt][qt][1], (f16)o[dt][qt][2], (f16)o[dt][qt][3]};
                *(f16x4*)&ob[(qt * 16 + lr) * 72 + dt * 16 + quad * 4] = oh;
            }
        const int rl = lane >> 3;   // 0..7
        const int ck = lane & 7;    // 16B chunk within the 128B head-row
#pragma unroll
        for (int i = 0; i < 4; i++) {
            const int row_l = rl + i * 8;
            f16x8 val = *(const f16x8*)&ob[row_l * 72 + ck * 8];
            *(f16x8*)&OpartH[((size_t)sp * TSEQ + wrow0 + row_l) * EMBED + h * DHEAD + ck * 8] = val;
        }
#pragma unroll
        for (int qt = 0; qt < 2; qt++)
            if (quad == 0) {
                int row = wrow0 + qt * 16 + lr;
                ml[((size_t)sp * TSEQ + row) * NHEAD + h] = make_float2(m_i[qt], l_i[qt]);
            }
    }
}

// ---------------- merge split-K f16 partials -> ctx f16 (vectorized f16x8 path)
__global__ __launch_bounds__(128) void attn_merge_kernel(const f16* __restrict__ OpartH,
                                                         const float2* __restrict__ ml,
                                                         f16* __restrict__ ctx) {
    const int row = blockIdx.x;
    const int t = threadIdx.x;
    __shared__ float wgt[NSPLIT][NHEAD];
    if (t < NHEAD) {
        float m[NSPLIT], l[NSPLIT];
        float M = -INFINITY;
#pragma unroll
        for (int s = 0; s < NSPLIT; s++) {
            float2 v = ml[((size_t)s * TSEQ + row) * NHEAD + t];
            m[s] = v.x; l[s] = v.y;
            M = fmaxf(M, m[s]);
        }
        float L = 0.f;
        float w[NSPLIT];
#pragma unroll
        for (int s = 0; s < NSPLIT; s++) {
            w[s] = exp2f(m[s] - M);
            L += l[s] * w[s];
        }
        float rL = 1.0f / L;
#pragma unroll
        for (int s = 0; s < NSPLIT; s++) wgt[s][t] = w[s] * rL;
    }
    __syncthreads();
    if (t < 96) {   // 96 chunks of 8 f16 = 768 cols
        const int h = t >> 3;   // 8 chunks per 64-wide head
        float acc[8] = {0.f, 0.f, 0.f, 0.f, 0.f, 0.f, 0.f, 0.f};
#pragma unroll
        for (int s = 0; s < NSPLIT; s++) {
            const float w = wgt[s][h];
            f16x8 v = *(const f16x8*)&OpartH[((size_t)s * TSEQ + row) * EMBED + t * 8];
#pragma unroll
            for (int e = 0; e < 8; e++) acc[e] += w * (float)v[e];
        }
        f16x8 out;
#pragma unroll
        for (int e = 0; e < 8; e++) out[e] = (f16)acc[e];
        *(f16x8*)&ctx[(size_t)row * EMBED + t * 8] = out;
    }
}

extern "C" void kernel_launch(void* const* d_in, const int* in_sizes, int n_in,
                              void* d_out, int out_size, void* d_ws, size_t ws_size,
                              hipStream_t stream) {
    const float* x     = (const float*)d_in[0];
    const float* Wq    = (const float*)d_in[1];
    const float* bq    = (const float*)d_in[2];
    const float* Wk    = (const float*)d_in[3];
    const float* bk    = (const float*)d_in[4];
    const float* Wv    = (const float*)d_in[5];
    const float* bv    = (const float*)d_in[6];
    const float* Wo    = (const float*)d_in[7];
    const float* bo    = (const float*)d_in[8];
    const float* ln1_g = (const float*)d_in[9];
    const float* ln1_b = (const float*)d_in[10];
    const float* ln2_g = (const float*)d_in[11];
    const float* ln2_b = (const float*)d_in[12];
    const float* W1    = (const float*)d_in[13];
    const float* b1    = (const float*)d_in[14];
    const float* W2    = (const float*)d_in[15];
    const float* b2    = (const float*)d_in[16];

    char* p = (char*)d_ws;
    auto alloc = [&](size_t bytes) -> void* {
        void* r = (void*)p;
        p += (bytes + 255) & ~(size_t)255;
        return r;
    };
    f16*   WqkvT = (f16*)alloc((size_t)CQKV * EMBED * 2);
    f16*   WoT   = (f16*)alloc((size_t)EMBED * EMBED * 2);
    f16*   W1T   = (f16*)alloc((size_t)FFN_D * EMBED * 2);
    f16*   W2T   = (f16*)alloc((size_t)EMBED * FFN_D * 2);
    float* bqkv  = (float*)alloc((size_t)CQKV * 4);
    f16*   hh    = (f16*)alloc((size_t)TSEQ * EMBED * 2);
    f16*   qkv   = (f16*)alloc((size_t)TSEQ * CQKV * 2);   // V third unused (vT direct)
    f16*   vT    = (f16*)alloc((size_t)EMBED * TSEQ * 2);
    f16*   ctx   = (f16*)alloc((size_t)TSEQ * EMBED * 2);
    float* x2    = (float*)alloc((size_t)TSEQ * EMBED * 4);
    f16*   h2h   = (f16*)alloc((size_t)TSEQ * EMBED * 2);
    f16*   m1    = (f16*)alloc((size_t)TSEQ * FFN_D * 2);
    int*   ctr   = (int*)alloc(256);

    // aliases (lifetime-disjoint):
    //   OpartH (25.2 MB f16) = m1 region  (attn+merge finish before FFN1 writes m1)
    //   mlbuf  (1.5 MB)      = x2 region  (merge reads before Wo writes x2)
    f16*    OpartH = m1;
    float2* mlbuf  = (float2*)x2;

    dim3 blk(256);
    prep_kernel<<<dim3(1729), blk, 0, stream>>>(Wq, Wk, Wv, Wo, W1, W2, bq, bk, bv,
                                                WqkvT, WoT, W1T, W2T, bqkv);
    // LN1 -> hh (f16)
    ln_kernel<<<dim3(TSEQ), blk, 0, stream>>>(x, ln1_g, ln1_b, hh);
    // QKV fused GEMM 64x128 KSTEP2 (49.2 KB LDS, 3/CU): grid 18x64 = 1152
    gemm_kernel<0, 64, 128, 2><<<dim3(CQKV / 128, TSEQ / 64), blk, 0, stream>>>(
        hh, WqkvT, bqkv, nullptr, nullptr, qkv, vT, TSEQ, CQKV, EMBED);
    // persistent attention (R1 structure: 8 XCD queues, NSPLIT=4, grid 768) + merge
    (void)hipMemsetAsync(ctr, 0, 256, stream);
    attn_kernel<<<dim3(768), blk, 0, stream>>>(qkv, vT, OpartH, mlbuf, ctr);
    attn_merge_kernel<<<dim3(TSEQ), dim3(128), 0, stream>>>(OpartH, mlbuf, ctx);
    // Wo GEMM 64x64 KSTEP2 + f16 residual(hh) -> fp32 x2: grid 768 = 3/CU exact
    gemm_kernel<1, 64, 64, 2><<<dim3(EMBED / 64, TSEQ / 64), blk, 0, stream>>>(
        ctx, WoT, bo, hh, x2, nullptr, nullptr, TSEQ, EMBED, EMBED);
    // LN2 -> h2h (f16)
    ln_kernel<<<dim3(TSEQ), blk, 0, stream>>>(x2, ln2_g, ln2_b, h2h);
    // FFN1 + gelu -> m1: 128x128 KSTEP1 (dbuf would be 65.6 KB = m132 trap), 768 = 3/CU
    gemm_kernel<2, 128, 128, 1><<<dim3(FFN_D / 128, TSEQ / 128), blk, 0, stream>>>(
        h2h, W1T, b1, nullptr, nullptr, m1, nullptr, TSEQ, FFN_D, EMBED);
    // FFN2 GEMM 64x64 KSTEP2 + f16 residual(h2h) -> fp32 d_out: grid 768 = 3/CU exact
    gemm_kernel<1, 64, 64, 2><<<dim3(EMBED / 64, TSEQ / 64), blk, 0, stream>>>(
        m1, W2T, b2, h2h, (float*)d_out, nullptr, nullptr, TSEQ, EMBED, FFN_D);
}